// Round 8
// baseline (878.619 us; speedup 1.0000x reference)
//
#include <hip/hip_runtime.h>
#include <hip/hip_bf16.h>
#include <math.h>

#define BB 64
#define SS 2048
#define MT (SS*BB)   // 131072 rows of the big GEMM
#define NT 8         // K-steps (K=1024, BK=128)

typedef __attribute__((ext_vector_type(4))) float f4;
typedef __attribute__((ext_vector_type(4))) int   i4;
typedef __attribute__((ext_vector_type(8))) int   i8;

__device__ __forceinline__ float fast_tanh(float x) {
  float t = __expf(2.0f * x);
  return 1.0f - 2.0f * __builtin_amdgcn_rcpf(t + 1.0f);
}

#define GLD16(gp, lp) __builtin_amdgcn_global_load_lds( \
    (const __attribute__((address_space(1))) void*)(gp), \
    (__attribute__((address_space(3))) void*)(lp), 16, 0, 0)
#define WAITV4() asm volatile("s_waitcnt vmcnt(4)" ::: "memory")
#define WAITV0() asm volatile("s_waitcnt vmcnt(0)" ::: "memory")
#define BAR()    __builtin_amdgcn_s_barrier()
#define SCHED0() __builtin_amdgcn_sched_barrier(0)

// ---- coalesced pack: f32 (rows x stride) -> swizzled fp8 e4m3 units.
// Global layout: [panel(256 rows)][kt 0..7][h=row>>7][r=row&127][8 slots x 16B]
// slot sp at row r holds source cols kt*128 + ((sp^(r&7))*16 ..+16).
// grid: (rows/64, 4); block 256.
__global__ void k_packq(const float* __restrict__ src, unsigned char* __restrict__ dst,
                        int stride) {
  __shared__ float ls[64][260];
  int g = blockIdx.x, cb = blockIdx.y, tid = threadIdx.x;
  int cl = (tid & 63) * 4, rbk = tid >> 6;
  const float* s0 = src + (size_t)(g * 64) * stride + cb * 256 + cl;
  #pragma unroll
  for (int it = 0; it < 16; ++it) {
    int rr = it * 4 + rbk;
    *(f4*)&ls[rr][cl] = *(const f4*)(s0 + (size_t)rr * stride);
  }
  __syncthreads();
  int rr = tid & 63;
  int q = tid >> 6;                 // 0..3: 64-col chunk
  int kt = cb * 2 + (q >> 1);
  int grow = g * 64 + rr;
  int panel = grow >> 8, pr = grow & 255, h = pr >> 7, r = pr & 127;
  int rx = r & 7;
  unsigned char* ub = dst + (((size_t)(panel * 8 + kt) * 2 + h) * 128 + r) * 128;
  #pragma unroll
  for (int si = 0; si < 4; ++si) {
    int s = (q & 1) * 4 + si;               // source 16B slot within the 128-col kstep
    int sp = s ^ rx;                        // inverse-swizzled destination slot
    const float* fp = &ls[rr][q * 64 + si * 16];
    i4 w;
    #pragma unroll
    for (int k = 0; k < 4; ++k) {
      int b = 0;
      b = __builtin_amdgcn_cvt_pk_fp8_f32(fp[k * 4 + 0], fp[k * 4 + 1], b, 0);
      b = __builtin_amdgcn_cvt_pk_fp8_f32(fp[k * 4 + 2], fp[k * 4 + 3], b, 1);
      w[k] = b;
    }
    *(i4*)(ub + sp * 16) = w;
  }
}

// ---- hp[b][a] = hidden[b,:]·Wd[a,:] + bias[a]
__global__ void k_hp(const float* __restrict__ hidden, const float* __restrict__ w,
                     const float* __restrict__ wbias, float* __restrict__ hp) {
  __shared__ float hs[1024];
  int b = blockIdx.x, tid = threadIdx.x;
  for (int i = tid; i < 1024; i += 256) hs[i] = hidden[b * 1024 + i];
  __syncthreads();
  int a = blockIdx.y * 256 + tid;
  const f4* wd = (const f4*)(w + a * 2048 + 1024);
  const f4* hv = (const f4*)hs;
  float acc = wbias[a];
  #pragma unroll 8
  for (int d = 0; d < 256; ++d) {
    f4 x = wd[d], y = hv[d];
    acc += x[0]*y[0] + x[1]*y[1] + x[2]*y[2] + x[3]*y[3];
  }
  hp[b * 1024 + a] = acc;
}

__device__ __forceinline__ i8 build8(i4 lo, i4 hi) {
  i8 r;
  r[0] = lo[0]; r[1] = lo[1]; r[2] = lo[2]; r[3] = lo[3];
  r[4] = hi[0]; r[5] = hi[1]; r[6] = hi[2]; r[7] = hi[3];
  return r;
}

// ---- fused GEMM, MX-fp8 (unit scales): 256x256 tile, BK=128, 8 waves (2Mx4N),
// per-wave 128x64. mfma_scale_f32_16x16x128_f8f6f4. A,B double-buffered LDS
// (2 x 64KB). 2 phases/K-step; stage A(t+1)@P0, B(t+2)@P1; vmcnt(4) boundary.
// partials[p][b][s], p = bn*4 + wc.
__global__ __launch_bounds__(512, 1) void k_gemm(
    const unsigned char* __restrict__ Aq, const unsigned char* __restrict__ Wq,
    const float* __restrict__ hp, const float* __restrict__ vw,
    float* __restrict__ part, int bm0, int nbm) {
  extern __shared__ char smem[];
  int bid = blockIdx.x;
  int nwg = nbm * 4;
  int wg = bid;
  if ((nwg & 7) == 0) { int cpx = nwg >> 3; wg = (bid & 7) * cpx + (bid >> 3); }
  int bn = wg & 3;              // bn fastest: 4 readers of one A-tile on one XCD
  int bmL = wg >> 2;
  int tid = threadIdx.x, lane = tid & 63;
  int wid = tid >> 6, wr = wid >> 2, wc = wid & 3;
  int c = lane & 15, kq = lane >> 4;

  // swizzled 16B-slot byte offsets within a 128B row
  int sx0 = ((2 * kq) ^ (c & 7)) << 4;
  int sx1 = sx0 ^ 16;
  int aoff0 = wr * 16384 + c * 128;                                   // + mi*2048 + sx
  int boff0 = 32768 + (wc >> 1) * 16384 + ((wc & 1) * 64 + c) * 128;  // + ni*2048 + sx

  const unsigned char* Abase = Aq + (size_t)bmL * 262144 + tid * 16;
  const unsigned char* Bbase = Wq + (size_t)bn * 262144 + tid * 16;
  auto stage = [&](int tt, int u) {   // u: 0=A-h0, 1=A-h1, 2=B-h0, 3=B-h1
    char* d = smem + (tt & 1) * 65536 + u * 16384 + tid * 16;
    const unsigned char* s = ((u & 2) ? Bbase : Abase) + ((size_t)tt * 2 + (u & 1)) * 16384;
    GLD16(s, d);
    GLD16(s + 8192, d + 8192);
  };

  f4 acc[8][4];
  f4 z = {0.f, 0.f, 0.f, 0.f};
  #pragma unroll
  for (int i = 0; i < 8; ++i)
    #pragma unroll
    for (int j = 0; j < 4; ++j) acc[i][j] = z;

  i8 a03[4], a47[4], bfr[4];

#define LD_A(DST, RB, MI0) { const char* p_ = (RB) + aoff0; \
    _Pragma("unroll") \
    for (int m_ = 0; m_ < 4; ++m_) { \
      i4 lo_ = *(const i4*)(p_ + ((MI0) + m_) * 2048 + sx0); \
      i4 hi_ = *(const i4*)(p_ + ((MI0) + m_) * 2048 + sx1); \
      DST[m_] = build8(lo_, hi_); } }
#define LD_B(DST, RB) { const char* p_ = (RB) + boff0; \
    _Pragma("unroll") \
    for (int n_ = 0; n_ < 4; ++n_) { \
      i4 lo_ = *(const i4*)(p_ + n_ * 2048 + sx0); \
      i4 hi_ = *(const i4*)(p_ + n_ * 2048 + sx1); \
      DST[n_] = build8(lo_, hi_); } }
#define MM(MB, VA, VB) { \
    __builtin_amdgcn_s_setprio(1); \
    _Pragma("unroll") \
    for (int m_ = 0; m_ < 4; ++m_) { \
      acc[(MB)+m_][0] = __builtin_amdgcn_mfma_scale_f32_16x16x128_f8f6f4(VA[m_], VB[0], acc[(MB)+m_][0], 0, 0, 0, 0x7F7F7F7F, 0, 0x7F7F7F7F); \
      acc[(MB)+m_][1] = __builtin_amdgcn_mfma_scale_f32_16x16x128_f8f6f4(VA[m_], VB[1], acc[(MB)+m_][1], 0, 0, 0, 0x7F7F7F7F, 0, 0x7F7F7F7F); \
      acc[(MB)+m_][2] = __builtin_amdgcn_mfma_scale_f32_16x16x128_f8f6f4(VA[m_], VB[2], acc[(MB)+m_][2], 0, 0, 0, 0x7F7F7F7F, 0, 0x7F7F7F7F); \
      acc[(MB)+m_][3] = __builtin_amdgcn_mfma_scale_f32_16x16x128_f8f6f4(VA[m_], VB[3], acc[(MB)+m_][3], 0, 0, 0, 0x7F7F7F7F, 0, 0x7F7F7F7F); \
    } \
    __builtin_amdgcn_s_setprio(0); }

  // prologue: A(0) h0,h1 + B(0) h0,h1 + B(1) h0,h1
  stage(0, 0); stage(0, 1); stage(0, 2); stage(0, 3);
  stage(1, 2); stage(1, 3);
  WAITV4();            // A(0)+B(0) landed; B(1) flies
  BAR();
  SCHED0();
  LD_A(a03, smem, 0);
  LD_B(bfr, smem);

  #pragma unroll 1
  for (int t = 0; t < NT; ++t) {
    const char* rb = smem + (t & 1) * 65536;
    // P0: MFMA mi0-3; stage A(t+1); prefetch a47
    if (t < 7) { stage(t + 1, 0); stage(t + 1, 1); }
    MM(0, a03, bfr);
    LD_A(a47, rb, 4);
    SCHED0();
    BAR();               // all waves consumed B(t) LDS (lgkm before their P0 MFMAs)
    SCHED0();
    // P1: MFMA mi4-7; stage B(t+2) into current buffer's B region
    if (t < 6) { stage(t + 2, 2); stage(t + 2, 3); }
    MM(4, a47, bfr);
    // boundary
    if (t < 7) {
      if (t < 6) WAITV4(); else WAITV0();
      SCHED0();
      BAR();
      SCHED0();
      const char* nb = smem + ((t + 1) & 1) * 65536;
      LD_A(a03, nb, 0);
      LD_B(bfr, nb);
    }
  }
#undef LD_A
#undef LD_B
#undef MM

  // ---- epilogue: stage hp[b][bn*256..+255] (64x256 f32 = 64KB) into LDS
  __syncthreads();
  {
    const float* hprow = hp + bn * 256;
    float* lhp = (float*)smem;
    #pragma unroll
    for (int qd = 0; qd < 8; ++qd) {
      int i = qd * 512 + tid;
      int b = i >> 6, col4 = i & 63;
      *(f4*)(lhp + b * 256 + col4 * 4) = *(const f4*)(hprow + (size_t)b * 1024 + col4 * 4);
    }
  }
  __syncthreads();
  const float* lhpf = (const float*)smem;

  int lg = kq;
  int bm = bm0 + bmL;
  float rs[8][4];
  #pragma unroll
  for (int mi = 0; mi < 8; ++mi)
    #pragma unroll
    for (int j = 0; j < 4; ++j) rs[mi][j] = 0.f;
  #pragma unroll
  for (int ni = 0; ni < 4; ++ni) {
    int colL = wc * 64 + ni * 16 + c;
    float vwa = vw[bn * 256 + colL];
    #pragma unroll
    for (int mi = 0; mi < 8; ++mi) {
      #pragma unroll
      for (int j = 0; j < 4; ++j) {
        int r = wr * 128 + mi * 16 + lg * 4 + j;
        int b = r & 63;
        float x = acc[mi][ni][j] + lhpf[b * 256 + colL];
        rs[mi][j] += fast_tanh(x) * vwa;
      }
    }
  }
  #pragma unroll
  for (int off = 1; off < 16; off <<= 1) {
    #pragma unroll
    for (int mi = 0; mi < 8; ++mi)
      #pragma unroll
      for (int j = 0; j < 4; ++j)
        rs[mi][j] += __shfl_xor(rs[mi][j], off, 64);
  }
  if (c == 0) {
    int p = bn * 4 + wc;
    #pragma unroll
    for (int mi = 0; mi < 8; ++mi)
      #pragma unroll
      for (int j = 0; j < 4; ++j) {
        int m = bm * 256 + wr * 128 + mi * 16 + lg * 4 + j;
        int b = m & 63, s = m >> 6;
        part[(size_t)p * MT + b * SS + s] = rs[mi][j];
      }
  }
}

// ---- sum 16 partials -> scores, softmax over s per b -> weights[b][s]
__global__ void k_softmax(const float* __restrict__ part, float* __restrict__ wt) {
  int b = blockIdx.x, tid = threadIdx.x, lane = tid & 63, wid = tid >> 6;
  __shared__ float red[8];
  float sc[8];
  float mx = -1e30f;
  #pragma unroll
  for (int i = 0; i < 8; ++i) {
    int s = tid + i * 256;
    float a = 0.f;
    #pragma unroll
    for (int p = 0; p < 16; ++p) a += part[(size_t)p * MT + b * SS + s];
    sc[i] = a; mx = fmaxf(mx, a);
  }
  for (int o = 1; o < 64; o <<= 1) mx = fmaxf(mx, __shfl_xor(mx, o, 64));
  if (lane == 0) red[wid] = mx;
  __syncthreads();
  mx = fmaxf(fmaxf(red[0], red[1]), fmaxf(red[2], red[3]));
  float sum = 0.f;
  #pragma unroll
  for (int i = 0; i < 8; ++i) { sc[i] = expf(sc[i] - mx); sum += sc[i]; }
  for (int o = 1; o < 64; o <<= 1) sum += __shfl_xor(sum, o, 64);
  if (lane == 0) red[4 + wid] = sum;
  __syncthreads();
  sum = red[4] + red[5] + red[6] + red[7];
  float inv = 1.f / sum;
  #pragma unroll
  for (int i = 0; i < 8; ++i) wt[b * SS + tid + i * 256] = sc[i] * inv;
}

// ---- context from f32 v: ctxp[cch][b][e] = sum_{s in chunk} w[b][s]*v[s][b][e]
__global__ void k_ctx_f32(const float* __restrict__ v, const float* __restrict__ wt,
                          float* __restrict__ ctxp) {
  int b = blockIdx.x, cch = blockIdx.y, tid = threadIdx.x;
  f4 acc = {0.f, 0.f, 0.f, 0.f};
  int s0 = cch * 128;
  const float* wrow = wt + b * SS;
  #pragma unroll 4
  for (int s = s0; s < s0 + 128; ++s) {
    float ws = wrow[s];
    const f4* vp = (const f4*)(v + (size_t)(s * 64 + b) * 1024);
    acc += vp[tid] * ws;
  }
  *(f4*)(ctxp + (size_t)(cch * 64 + b) * 1024 + tid * 4) = acc;
}

__global__ void k_out(const float* __restrict__ ctxp, float* __restrict__ out) {
  int b = blockIdx.x, tid = threadIdx.x;
  f4 acc = {0.f, 0.f, 0.f, 0.f};
  #pragma unroll
  for (int cch = 0; cch < 16; ++cch)
    acc += *(const f4*)(ctxp + (size_t)(cch * 64 + b) * 1024 + tid * 4);
  *(f4*)(out + b * 1024 + tid * 4) = acc;
}

extern "C" void kernel_launch(void* const* d_in, const int* in_sizes, int n_in,
                              void* d_out, int out_size, void* d_ws, size_t ws_size,
                              hipStream_t stream) {
  const float* hidden = (const float*)d_in[0];
  const float* v      = (const float*)d_in[1];   // (S, B, ENC) rows s*64+b
  const float* ww     = (const float*)d_in[2];   // (1024, 2048)
  const float* wbias  = (const float*)d_in[3];   // (1024)
  const float* vwgt   = (const float*)d_in[4];   // (1, 1024)
  float* out = (float*)d_out;

  char* ws = (char*)d_ws;
  float*          hp   = (float*)(ws);                                   // 256 KB
  unsigned char*  wq   = (unsigned char*)(ws + 262144);                  // 1 MB fp8 We
  float*          part = (float*)(ws + 262144 + 1048576);                // 8 MB
  float*          wt   = (float*)(ws + 262144 + 1048576 + 8388608);      // 512 KB
  float*          ctxp = (float*)(ws + 262144 + 1048576 + 8388608 + 524288); // 4 MB
  size_t fixed = 262144 + 1048576 + 8388608 + 524288 + 4194304;
  unsigned char*  vq   = (unsigned char*)(ws + fixed);                   // 128 MB fp8 v

  size_t avail = (ws_size > fixed) ? (ws_size - fixed) : 0;
  long rows_chunk = (long)(avail / 1024) & ~511L;      // fp8 row = 1024 B
  if (rows_chunk > MT) rows_chunk = MT;
  if (rows_chunk < 512) rows_chunk = 512;

  hipFuncSetAttribute((const void*)k_gemm, hipFuncAttributeMaxDynamicSharedMemorySize, 131072);

  k_packq<<<dim3(16, 4), 256, 0, stream>>>(ww, wq, 2048);
  k_hp<<<dim3(64, 4), 256, 0, stream>>>(hidden, ww, wbias, hp);

  for (long r0 = 0; r0 < MT; r0 += rows_chunk) {
    long nr = MT - r0; if (nr > rows_chunk) nr = rows_chunk;
    int nbm = (int)(nr / 256);
    k_packq<<<dim3((int)(nr / 64), 4), 256, 0, stream>>>(v + (size_t)r0 * 1024, vq, 1024);
    k_gemm<<<nbm * 4, 512, 131072, stream>>>(vq, wq, hp, vwgt, part, (int)(r0 / 256), nbm);
  }

  k_softmax<<<64, 256, 0, stream>>>(part, wt);
  k_ctx_f32<<<dim3(64, 16), 256, 0, stream>>>(v, wt, ctxp);
  k_out<<<64, 256, 0, stream>>>(ctxp, out);
}

// Round 9
// 876.238 us; speedup vs baseline: 1.0027x; 1.0027x over previous
//
#include <hip/hip_runtime.h>
#include <hip/hip_bf16.h>
#include <math.h>

#define BB 64
#define SS 2048
#define MT (SS*BB)   // 131072 rows of the big GEMM
#define NT 8         // K-steps (K=1024, BK=128)

typedef __attribute__((ext_vector_type(4))) float f4;
typedef __attribute__((ext_vector_type(4))) int   i4;
typedef __attribute__((ext_vector_type(8))) int   i8;

__device__ __forceinline__ float fast_tanh(float x) {
  float t = __expf(2.0f * x);
  return 1.0f - 2.0f * __builtin_amdgcn_rcpf(t + 1.0f);
}

__device__ __forceinline__ f4 mmq(i8 a, i8 b, f4 c) {
  return __builtin_amdgcn_mfma_scale_f32_16x16x128_f8f6f4(
      a, b, c, 0, 0, 0, 0x7F7F7F7F, 0, 0x7F7F7F7F);
}

#define GLD16(gp, lp) __builtin_amdgcn_global_load_lds( \
    (const __attribute__((address_space(1))) void*)(gp), \
    (__attribute__((address_space(3))) void*)(lp), 16, 0, 0)
#define WAITV4() asm volatile("s_waitcnt vmcnt(4)" ::: "memory")
#define WAITV0() asm volatile("s_waitcnt vmcnt(0)" ::: "memory")
#define BAR()    __builtin_amdgcn_s_barrier()
#define SCHED0() __builtin_amdgcn_sched_barrier(0)

// ---- coalesced pack: f32 (rows x stride) -> swizzled fp8 e4m3 units.
// Global layout: [panel(256 rows)][kt 0..7][h=row>>7][r=row&127][8 slots x 16B]
// slot sp at row r holds source cols kt*128 + ((sp^(r&7))*16 ..+16).
// grid: (rows/64, 4); block 256.
__global__ void k_packq(const float* __restrict__ src, unsigned char* __restrict__ dst,
                        int stride) {
  __shared__ float ls[64][260];
  int g = blockIdx.x, cb = blockIdx.y, tid = threadIdx.x;
  int cl = (tid & 63) * 4, rbk = tid >> 6;
  const float* s0 = src + (size_t)(g * 64) * stride + cb * 256 + cl;
  #pragma unroll
  for (int it = 0; it < 16; ++it) {
    int rr = it * 4 + rbk;
    *(f4*)&ls[rr][cl] = *(const f4*)(s0 + (size_t)rr * stride);
  }
  __syncthreads();
  int rr = tid & 63;
  int q = tid >> 6;                 // 0..3: 64-col chunk
  int kt = cb * 2 + (q >> 1);
  int grow = g * 64 + rr;
  int panel = grow >> 8, pr = grow & 255, h = pr >> 7, r = pr & 127;
  int rx = r & 7;
  unsigned char* ub = dst + (((size_t)(panel * 8 + kt) * 2 + h) * 128 + r) * 128;
  #pragma unroll
  for (int si = 0; si < 4; ++si) {
    int s = (q & 1) * 4 + si;               // source 16B slot within the 128-col kstep
    int sp = s ^ rx;                        // inverse-swizzled destination slot
    const float* fp = &ls[rr][q * 64 + si * 16];
    i4 w;
    #pragma unroll
    for (int k = 0; k < 4; ++k) {
      int b = 0;
      b = __builtin_amdgcn_cvt_pk_fp8_f32(fp[k * 4 + 0], fp[k * 4 + 1], b, 0);
      b = __builtin_amdgcn_cvt_pk_fp8_f32(fp[k * 4 + 2], fp[k * 4 + 3], b, 1);
      w[k] = b;
    }
    *(i4*)(ub + sp * 16) = w;
  }
}

// ---- hp[b][a] = hidden[b,:]·Wd[a,:] + bias[a]
__global__ void k_hp(const float* __restrict__ hidden, const float* __restrict__ w,
                     const float* __restrict__ wbias, float* __restrict__ hp) {
  __shared__ float hs[1024];
  int b = blockIdx.x, tid = threadIdx.x;
  for (int i = tid; i < 1024; i += 256) hs[i] = hidden[b * 1024 + i];
  __syncthreads();
  int a = blockIdx.y * 256 + tid;
  const f4* wd = (const f4*)(w + a * 2048 + 1024);
  const f4* hv = (const f4*)hs;
  float acc = wbias[a];
  #pragma unroll 8
  for (int d = 0; d < 256; ++d) {
    f4 x = wd[d], y = hv[d];
    acc += x[0]*y[0] + x[1]*y[1] + x[2]*y[2] + x[3]*y[3];
  }
  hp[b * 1024 + a] = acc;
}

// ---- fused GEMM, MX-fp8 (unit scales): 256x256 tile, BK=128, 8 waves (2Mx4N),
// per-wave 128x64. All fragments in NAMED i8 registers (no arrays -> no scratch).
// A,B double-buffered LDS (2 x 64KB). 2 phases/K-step; stage A(t+1)@P0,
// B(t+2)@P1; counted vmcnt(4) boundary. partials[p][b][s], p = bn*4 + wc.
__global__ __launch_bounds__(512, 1) void k_gemm(
    const unsigned char* __restrict__ Aq, const unsigned char* __restrict__ Wq,
    const float* __restrict__ hp, const float* __restrict__ vw,
    float* __restrict__ part, int bm0, int nbm) {
  extern __shared__ char smem[];
  int bid = blockIdx.x;
  int nwg = nbm * 4;
  int wg = bid;
  if ((nwg & 7) == 0) { int cpx = nwg >> 3; wg = (bid & 7) * cpx + (bid >> 3); }
  int bn = wg & 3;              // bn fastest: 4 readers of one A-tile on one XCD
  int bmL = wg >> 2;
  int tid = threadIdx.x, lane = tid & 63;
  int wid = tid >> 6, wr = wid >> 2, wc = wid & 3;
  int c = lane & 15, kq = lane >> 4;

  // swizzled 16B-slot byte offsets within a 128B row
  int sx0 = ((2 * kq) ^ (c & 7)) << 4;
  int sx1 = sx0 ^ 16;
  int aoff0 = wr * 16384 + c * 128;                                   // + mi*2048 + sx
  int boff0 = 32768 + (wc >> 1) * 16384 + ((wc & 1) * 64 + c) * 128;  // + ni*2048 + sx

  const unsigned char* Abase = Aq + (size_t)bmL * 262144 + tid * 16;
  const unsigned char* Bbase = Wq + (size_t)bn * 262144 + tid * 16;
  auto stage = [&](int tt, int u) {   // u: 0=A-h0, 1=A-h1, 2=B-h0, 3=B-h1
    char* d = smem + (tt & 1) * 65536 + u * 16384 + tid * 16;
    const unsigned char* s = ((u & 2) ? Bbase : Abase) + ((size_t)tt * 2 + (u & 1)) * 16384;
    GLD16(s, d);
    GLD16(s + 8192, d + 8192);
  };

  f4 acc[8][4];
  f4 z = {0.f, 0.f, 0.f, 0.f};
  #pragma unroll
  for (int i = 0; i < 8; ++i)
    #pragma unroll
    for (int j = 0; j < 4; ++j) acc[i][j] = z;

  i8 a0, a1, a2, a3, a4, a5, a6, a7, b0, b1, b2, b3;

#define LD2(DST, ADDR) { \
    i4 lo_ = *(const i4*)((ADDR) + sx0); \
    i4 hi_ = *(const i4*)((ADDR) + sx1); \
    DST = __builtin_shufflevector(lo_, hi_, 0, 1, 2, 3, 4, 5, 6, 7); }
#define MMR(MI, VA) \
    acc[MI][0] = mmq(VA, b0, acc[MI][0]); \
    acc[MI][1] = mmq(VA, b1, acc[MI][1]); \
    acc[MI][2] = mmq(VA, b2, acc[MI][2]); \
    acc[MI][3] = mmq(VA, b3, acc[MI][3]);

  // prologue: A(0) h0,h1 + B(0) h0,h1 + B(1) h0,h1
  stage(0, 0); stage(0, 1); stage(0, 2); stage(0, 3);
  stage(1, 2); stage(1, 3);
  WAITV4();            // A(0)+B(0) landed; B(1) flies
  BAR();
  SCHED0();
  {
    const char* ab = smem + aoff0;
    const char* bb = smem + boff0;
    LD2(a0, ab);  LD2(a1, ab + 2048);  LD2(a2, ab + 4096);  LD2(a3, ab + 6144);
    LD2(b0, bb);  LD2(b1, bb + 2048);  LD2(b2, bb + 4096);  LD2(b3, bb + 6144);
  }

  #pragma unroll 1
  for (int t = 0; t < NT; ++t) {
    const char* rb = smem + (t & 1) * 65536;
    const char* ab = rb + aoff0;
    // P0: MFMA mi0-3; stage A(t+1); read mi4-7 frags
    if (t < 7) { stage(t + 1, 0); stage(t + 1, 1); }
    __builtin_amdgcn_s_setprio(1);
    MMR(0, a0); MMR(1, a1); MMR(2, a2); MMR(3, a3);
    __builtin_amdgcn_s_setprio(0);
    LD2(a4, ab + 8192);  LD2(a5, ab + 10240);
    LD2(a6, ab + 12288); LD2(a7, ab + 14336);
    SCHED0();
    BAR();               // all waves' B(t) reads drained before P1 overwrites B-region
    SCHED0();
    // P1: MFMA mi4-7; stage B(t+2) into current buffer's B region
    if (t < 6) { stage(t + 2, 2); stage(t + 2, 3); }
    __builtin_amdgcn_s_setprio(1);
    MMR(4, a4); MMR(5, a5); MMR(6, a6); MMR(7, a7);
    __builtin_amdgcn_s_setprio(0);
    // boundary
    if (t < 7) {
      if (t < 6) WAITV4(); else WAITV0();
      SCHED0();
      BAR();
      SCHED0();
      const char* nab = smem + ((t + 1) & 1) * 65536 + aoff0;
      const char* nbb = smem + ((t + 1) & 1) * 65536 + boff0;
      LD2(a0, nab);  LD2(a1, nab + 2048);  LD2(a2, nab + 4096);  LD2(a3, nab + 6144);
      LD2(b0, nbb);  LD2(b1, nbb + 2048);  LD2(b2, nbb + 4096);  LD2(b3, nbb + 6144);
    }
  }
#undef LD2
#undef MMR

  // ---- epilogue: stage hp[b][bn*256..+255] (64x256 f32 = 64KB) into LDS
  __syncthreads();
  {
    const float* hprow = hp + bn * 256;
    float* lhp = (float*)smem;
    #pragma unroll
    for (int qd = 0; qd < 8; ++qd) {
      int i = qd * 512 + tid;
      int b = i >> 6, col4 = i & 63;
      *(f4*)(lhp + b * 256 + col4 * 4) = *(const f4*)(hprow + (size_t)b * 1024 + col4 * 4);
    }
  }
  __syncthreads();
  const float* lhpf = (const float*)smem;

  int lg = kq;
  int bm = bm0 + bmL;
  float rs[8][4];
  #pragma unroll
  for (int mi = 0; mi < 8; ++mi)
    #pragma unroll
    for (int j = 0; j < 4; ++j) rs[mi][j] = 0.f;
  #pragma unroll
  for (int ni = 0; ni < 4; ++ni) {
    int colL = wc * 64 + ni * 16 + c;
    float vwa = vw[bn * 256 + colL];
    #pragma unroll
    for (int mi = 0; mi < 8; ++mi) {
      #pragma unroll
      for (int j = 0; j < 4; ++j) {
        int r = wr * 128 + mi * 16 + lg * 4 + j;
        int b = r & 63;
        float x = acc[mi][ni][j] + lhpf[b * 256 + colL];
        rs[mi][j] += fast_tanh(x) * vwa;
      }
    }
  }
  #pragma unroll
  for (int off = 1; off < 16; off <<= 1) {
    #pragma unroll
    for (int mi = 0; mi < 8; ++mi)
      #pragma unroll
      for (int j = 0; j < 4; ++j)
        rs[mi][j] += __shfl_xor(rs[mi][j], off, 64);
  }
  if (c == 0) {
    int p = bn * 4 + wc;
    #pragma unroll
    for (int mi = 0; mi < 8; ++mi)
      #pragma unroll
      for (int j = 0; j < 4; ++j) {
        int m = bm * 256 + wr * 128 + mi * 16 + lg * 4 + j;
        int b = m & 63, s = m >> 6;
        part[(size_t)p * MT + b * SS + s] = rs[mi][j];
      }
  }
}

// ---- sum 16 partials -> scores, softmax over s per b -> weights[b][s]
__global__ void k_softmax(const float* __restrict__ part, float* __restrict__ wt) {
  int b = blockIdx.x, tid = threadIdx.x, lane = tid & 63, wid = tid >> 6;
  __shared__ float red[8];
  float sc[8];
  float mx = -1e30f;
  #pragma unroll
  for (int i = 0; i < 8; ++i) {
    int s = tid + i * 256;
    float a = 0.f;
    #pragma unroll
    for (int p = 0; p < 16; ++p) a += part[(size_t)p * MT + b * SS + s];
    sc[i] = a; mx = fmaxf(mx, a);
  }
  for (int o = 1; o < 64; o <<= 1) mx = fmaxf(mx, __shfl_xor(mx, o, 64));
  if (lane == 0) red[wid] = mx;
  __syncthreads();
  mx = fmaxf(fmaxf(red[0], red[1]), fmaxf(red[2], red[3]));
  float sum = 0.f;
  #pragma unroll
  for (int i = 0; i < 8; ++i) { sc[i] = expf(sc[i] - mx); sum += sc[i]; }
  for (int o = 1; o < 64; o <<= 1) sum += __shfl_xor(sum, o, 64);
  if (lane == 0) red[4 + wid] = sum;
  __syncthreads();
  sum = red[4] + red[5] + red[6] + red[7];
  float inv = 1.f / sum;
  #pragma unroll
  for (int i = 0; i < 8; ++i) wt[b * SS + tid + i * 256] = sc[i] * inv;
}

// ---- context from f32 v: ctxp[cch][b][e] = sum_{s in chunk} w[b][s]*v[s][b][e]
__global__ void k_ctx_f32(const float* __restrict__ v, const float* __restrict__ wt,
                          float* __restrict__ ctxp) {
  int b = blockIdx.x, cch = blockIdx.y, tid = threadIdx.x;
  f4 acc = {0.f, 0.f, 0.f, 0.f};
  int s0 = cch * 128;
  const float* wrow = wt + b * SS;
  #pragma unroll 4
  for (int s = s0; s < s0 + 128; ++s) {
    float ws = wrow[s];
    const f4* vp = (const f4*)(v + (size_t)(s * 64 + b) * 1024);
    acc += vp[tid] * ws;
  }
  *(f4*)(ctxp + (size_t)(cch * 64 + b) * 1024 + tid * 4) = acc;
}

__global__ void k_out(const float* __restrict__ ctxp, float* __restrict__ out) {
  int b = blockIdx.x, tid = threadIdx.x;
  f4 acc = {0.f, 0.f, 0.f, 0.f};
  #pragma unroll
  for (int cch = 0; cch < 16; ++cch)
    acc += *(const f4*)(ctxp + (size_t)(cch * 64 + b) * 1024 + tid * 4);
  *(f4*)(out + b * 1024 + tid * 4) = acc;
}

extern "C" void kernel_launch(void* const* d_in, const int* in_sizes, int n_in,
                              void* d_out, int out_size, void* d_ws, size_t ws_size,
                              hipStream_t stream) {
  const float* hidden = (const float*)d_in[0];
  const float* v      = (const float*)d_in[1];   // (S, B, ENC) rows s*64+b
  const float* ww     = (const float*)d_in[2];   // (1024, 2048)
  const float* wbias  = (const float*)d_in[3];   // (1024)
  const float* vwgt   = (const float*)d_in[4];   // (1, 1024)
  float* out = (float*)d_out;

  char* ws = (char*)d_ws;
  float*          hp   = (float*)(ws);                                   // 256 KB
  unsigned char*  wq   = (unsigned char*)(ws + 262144);                  // 1 MB fp8 We
  float*          part = (float*)(ws + 262144 + 1048576);                // 8 MB
  float*          wt   = (float*)(ws + 262144 + 1048576 + 8388608);      // 512 KB
  float*          ctxp = (float*)(ws + 262144 + 1048576 + 8388608 + 524288); // 4 MB
  size_t fixed = 262144 + 1048576 + 8388608 + 524288 + 4194304;
  unsigned char*  vq   = (unsigned char*)(ws + fixed);                   // 128 MB fp8 v

  size_t avail = (ws_size > fixed) ? (ws_size - fixed) : 0;
  long rows_chunk = (long)(avail / 1024) & ~511L;      // fp8 row = 1024 B
  if (rows_chunk > MT) rows_chunk = MT;
  if (rows_chunk < 512) rows_chunk = 512;

  hipFuncSetAttribute((const void*)k_gemm, hipFuncAttributeMaxDynamicSharedMemorySize, 131072);

  k_packq<<<dim3(16, 4), 256, 0, stream>>>(ww, wq, 2048);
  k_hp<<<dim3(64, 4), 256, 0, stream>>>(hidden, ww, wbias, hp);

  for (long r0 = 0; r0 < MT; r0 += rows_chunk) {
    long nr = MT - r0; if (nr > rows_chunk) nr = rows_chunk;
    int nbm = (int)(nr / 256);
    k_packq<<<dim3((int)(nr / 64), 4), 256, 0, stream>>>(v + (size_t)r0 * 1024, vq, 1024);
    k_gemm<<<nbm * 4, 512, 131072, stream>>>(vq, wq, hp, vwgt, part, (int)(r0 / 256), nbm);
  }

  k_softmax<<<64, 256, 0, stream>>>(part, wt);
  k_ctx_f32<<<dim3(64, 16), 256, 0, stream>>>(v, wt, ctxp);
  k_out<<<64, 256, 0, stream>>>(ctxp, out);
}

// Round 11
// 556.114 us; speedup vs baseline: 1.5799x; 1.5756x over previous
//
#include <hip/hip_runtime.h>
#include <hip/hip_bf16.h>
#include <math.h>

#define BB 64
#define SS 2048
#define MT (SS*BB)   // 131072 rows of the big GEMM
#define NT 8         // K-steps (K=1024, BK=128)

typedef __attribute__((ext_vector_type(4))) float f4;
typedef __attribute__((ext_vector_type(4))) int   i4;

__device__ __forceinline__ float fast_tanh(float x) {
  float t = __expf(2.0f * x);
  return 1.0f - 2.0f * __builtin_amdgcn_rcpf(t + 1.0f);
}

#define GLD16(gp, lp) __builtin_amdgcn_global_load_lds( \
    (const __attribute__((address_space(1))) void*)(gp), \
    (__attribute__((address_space(3))) void*)(lp), 16, 0, 0)
#define WAITV4() asm volatile("s_waitcnt vmcnt(4)" ::: "memory")
#define WAITV0() asm volatile("s_waitcnt vmcnt(0)" ::: "memory")
#define BAR()    __builtin_amdgcn_s_barrier()
#define SCHED0() __builtin_amdgcn_sched_barrier(0)

// ---- coalesced pack: f32 (rows x stride) -> swizzled fp8 e4m3 units.
// Global layout: [panel(256 rows)][kt 0..7][h=row>>7][r=row&127][8 slots x 16B]
// phys slot sp at row r holds source cols kt*128 + ((sp^(r&7))*16 ..+16).
// grid: (rows/64, 4); block 256.
__global__ void k_packq(const float* __restrict__ src, unsigned char* __restrict__ dst,
                        int stride) {
  __shared__ float ls[64][260];
  int g = blockIdx.x, cb = blockIdx.y, tid = threadIdx.x;
  int cl = (tid & 63) * 4, rbk = tid >> 6;
  const float* s0 = src + (size_t)(g * 64) * stride + cb * 256 + cl;
  #pragma unroll
  for (int it = 0; it < 16; ++it) {
    int rr = it * 4 + rbk;
    *(f4*)&ls[rr][cl] = *(const f4*)(s0 + (size_t)rr * stride);
  }
  __syncthreads();
  int rr = tid & 63;
  int q = tid >> 6;                 // 0..3: 64-col chunk
  int kt = cb * 2 + (q >> 1);
  int grow = g * 64 + rr;
  int panel = grow >> 8, pr = grow & 255, h = pr >> 7, r = pr & 127;
  int rx = r & 7;
  unsigned char* ub = dst + (((size_t)(panel * 8 + kt) * 2 + h) * 128 + r) * 128;
  #pragma unroll
  for (int si = 0; si < 4; ++si) {
    int s = (q & 1) * 4 + si;               // logical 16B slot within the 128-col kstep
    int sp = s ^ rx;                        // inverse-swizzled physical slot
    const float* fp = &ls[rr][q * 64 + si * 16];
    i4 w;
    #pragma unroll
    for (int k = 0; k < 4; ++k) {
      int b = 0;
      b = __builtin_amdgcn_cvt_pk_fp8_f32(fp[k * 4 + 0], fp[k * 4 + 1], b, 0);
      b = __builtin_amdgcn_cvt_pk_fp8_f32(fp[k * 4 + 2], fp[k * 4 + 3], b, 1);
      w[k] = b;
    }
    *(i4*)(ub + sp * 16) = w;
  }
}

// ---- hp[b][a] = hidden[b,:]·Wd[a,:] + bias[a]
__global__ void k_hp(const float* __restrict__ hidden, const float* __restrict__ w,
                     const float* __restrict__ wbias, float* __restrict__ hp) {
  __shared__ float hs[1024];
  int b = blockIdx.x, tid = threadIdx.x;
  for (int i = tid; i < 1024; i += 256) hs[i] = hidden[b * 1024 + i];
  __syncthreads();
  int a = blockIdx.y * 256 + tid;
  const f4* wd = (const f4*)(w + a * 2048 + 1024);
  const f4* hv = (const f4*)hs;
  float acc = wbias[a];
  #pragma unroll 8
  for (int d = 0; d < 256; ++d) {
    f4 x = wd[d], y = hv[d];
    acc += x[0]*y[0] + x[1]*y[1] + x[2]*y[2] + x[3]*y[3];
  }
  hp[b * 1024 + a] = acc;
}

// ---- fused GEMM, fp8 e4m3 (non-scaled 16x16x32): 256x256 tile, BK=128,
// 8 waves (2M x 4N), per-wave 128x64. R7-proven loop skeleton: 4 ks-phases
// per K-step, all B(t) frags register-resident by end-P1, BAR, then B(t+2)
// staging; counted vmcnt(4) at boundary. partials[p][b][s], p = bn*4 + wc.
__global__ __launch_bounds__(512, 1) void k_gemm(
    const unsigned char* __restrict__ Aq, const unsigned char* __restrict__ Wq,
    const float* __restrict__ hp, const float* __restrict__ vw,
    float* __restrict__ part, int bm0, int nbm) {
  extern __shared__ char smem[];
  int bid = blockIdx.x;
  int nwg = nbm * 4;
  int wg = bid;
  if ((nwg & 7) == 0) { int cpx = nwg >> 3; wg = (bid & 7) * cpx + (bid >> 3); }
  int bn = wg & 3;              // bn fastest: 4 readers of one A-tile on one XCD
  int bmL = wg >> 2;
  int tid = threadIdx.x, lane = tid & 63;
  int wid = tid >> 6, wr = wid >> 2, wc = wid & 3;
  int c = lane & 15, kq = lane >> 4;

  // per-ks slot byte offsets: logical slot L = ks*2 + (kq>>1), phys = L^(c&7),
  // byte = phys*16 + (kq&1)*8
  int cx = c & 7, ko = (kq & 1) << 3, kh = kq >> 1;
  int sx0 = (((0 + kh) ^ cx) << 4) + ko;
  int sx1 = (((2 + kh) ^ cx) << 4) + ko;
  int sx2 = (((4 + kh) ^ cx) << 4) + ko;
  int sx3 = (((6 + kh) ^ cx) << 4) + ko;
  int aoff = wr * 16384 + c * 128;                                   // + mi*2048 + sx
  int boff = 32768 + (wc >> 1) * 16384 + ((wc & 1) * 64 + c) * 128;  // + ni*2048 + sx

  const unsigned char* Abase = Aq + (size_t)bmL * 262144 + tid * 16;
  const unsigned char* Bbase = Wq + (size_t)bn * 262144 + tid * 16;
  auto stage = [&](int tt, int u) {   // u: 0=A-h0, 1=A-h1, 2=B-h0, 3=B-h1
    char* d = smem + (tt & 1) * 65536 + u * 16384 + tid * 16;
    const unsigned char* s = ((u & 2) ? Bbase : Abase) + ((size_t)tt * 2 + (u & 1)) * 16384;
    GLD16(s, d);
    GLD16(s + 8192, d + 8192);
  };

  f4 acc[8][4];
  f4 z = {0.f, 0.f, 0.f, 0.f};
  #pragma unroll
  for (int i = 0; i < 8; ++i)
    #pragma unroll
    for (int j = 0; j < 4; ++j) acc[i][j] = z;

  long ca0, ca1, ca2, ca3, ca4, ca5, ca6, ca7;
  long na0, na1, na2, na3, na4, na5, na6, na7;
  long b00, b01, b02, b03, b10, b11, b12, b13;
  long b20, b21, b22, b23, b30, b31, b32, b33;

#define RDA(A0,A1,A2,A3,A4,A5,A6,A7, BP, SX) { const char* p_ = (BP) + (SX); \
    A0 = *(const long*)(p_);          A1 = *(const long*)(p_ + 2048); \
    A2 = *(const long*)(p_ + 4096);   A3 = *(const long*)(p_ + 6144); \
    A4 = *(const long*)(p_ + 8192);   A5 = *(const long*)(p_ + 10240); \
    A6 = *(const long*)(p_ + 12288);  A7 = *(const long*)(p_ + 14336); }
#define RDB(B0,B1,B2,B3, BP, SX) { const char* p_ = (BP) + (SX); \
    B0 = *(const long*)(p_);          B1 = *(const long*)(p_ + 2048); \
    B2 = *(const long*)(p_ + 4096);   B3 = *(const long*)(p_ + 6144); }
#define MROW(MI, AV, B0,B1,B2,B3) \
    acc[MI][0] = __builtin_amdgcn_mfma_f32_16x16x32_fp8_fp8(AV, B0, acc[MI][0], 0, 0, 0); \
    acc[MI][1] = __builtin_amdgcn_mfma_f32_16x16x32_fp8_fp8(AV, B1, acc[MI][1], 0, 0, 0); \
    acc[MI][2] = __builtin_amdgcn_mfma_f32_16x16x32_fp8_fp8(AV, B2, acc[MI][2], 0, 0, 0); \
    acc[MI][3] = __builtin_amdgcn_mfma_f32_16x16x32_fp8_fp8(AV, B3, acc[MI][3], 0, 0, 0);
#define MM32(A0,A1,A2,A3,A4,A5,A6,A7, B0,B1,B2,B3) { \
    __builtin_amdgcn_s_setprio(1); \
    MROW(0, A0, B0,B1,B2,B3)  MROW(1, A1, B0,B1,B2,B3) \
    MROW(2, A2, B0,B1,B2,B3)  MROW(3, A3, B0,B1,B2,B3) \
    MROW(4, A4, B0,B1,B2,B3)  MROW(5, A5, B0,B1,B2,B3) \
    MROW(6, A6, B0,B1,B2,B3)  MROW(7, A7, B0,B1,B2,B3) \
    __builtin_amdgcn_s_setprio(0); }

  // prologue: A(0) 4 GLD + B(0) 4 GLD + B(1) 4 GLD
  stage(0, 0); stage(0, 1); stage(0, 2); stage(0, 3);
  stage(1, 2); stage(1, 3);
  WAITV4();            // A(0)+B(0) landed; B(1)'s 4 fly
  BAR();
  SCHED0();
  {
    const char* ab = smem + aoff;
    const char* bb = smem + boff;
    RDB(b00, b01, b02, b03, bb, sx0);
    RDB(b10, b11, b12, b13, bb, sx1);
    RDB(b20, b21, b22, b23, bb, sx2);
    RDB(b30, b31, b32, b33, bb, sx3);
    RDA(ca0, ca1, ca2, ca3, ca4, ca5, ca6, ca7, ab, sx0);
  }

  #pragma unroll 1
  for (int t = 0; t < NT; ++t) {
    const char* ab = smem + (t & 1) * 65536 + aoff;
    // P0: MM(ks0); read A-ks1; stage A(t+1,h0)
    if (t < 7) stage(t + 1, 0);
    MM32(ca0, ca1, ca2, ca3, ca4, ca5, ca6, ca7, b00, b01, b02, b03);
    RDA(na0, na1, na2, na3, na4, na5, na6, na7, ab, sx1);
    // P1: MM(ks1); read A-ks2; stage A(t+1,h1)
    if (t < 7) stage(t + 1, 1);
    MM32(na0, na1, na2, na3, na4, na5, na6, na7, b10, b11, b12, b13);
    RDA(ca0, ca1, ca2, ca3, ca4, ca5, ca6, ca7, ab, sx2);
    SCHED0();
    BAR();               // all waves' B(t)/A(t)-early LDS reads complete
    SCHED0();
    // P2: MM(ks2); read A-ks3; stage B(t+2,h0) into current buffer's B region
    if (t < 6) stage(t + 2, 2);
    MM32(ca0, ca1, ca2, ca3, ca4, ca5, ca6, ca7, b20, b21, b22, b23);
    RDA(na0, na1, na2, na3, na4, na5, na6, na7, ab, sx3);
    // P3: MM(ks3); stage B(t+2,h1)
    if (t < 6) stage(t + 2, 3);
    MM32(na0, na1, na2, na3, na4, na5, na6, na7, b30, b31, b32, b33);
    // boundary: A(t+1)+B(t+1) landed; B(t+2) may fly
    if (t < 7) {
      if (t < 6) WAITV4(); else WAITV0();
      SCHED0();
      BAR();
      SCHED0();
      const char* nab = smem + ((t + 1) & 1) * 65536 + aoff;
      const char* nbb = smem + ((t + 1) & 1) * 65536 + boff;
      RDB(b00, b01, b02, b03, nbb, sx0);
      RDB(b10, b11, b12, b13, nbb, sx1);
      RDB(b20, b21, b22, b23, nbb, sx2);
      RDB(b30, b31, b32, b33, nbb, sx3);
      RDA(ca0, ca1, ca2, ca3, ca4, ca5, ca6, ca7, nab, sx0);
    }
  }
#undef RDA
#undef RDB
#undef MROW
#undef MM32

  // ---- epilogue: stage hp[b][bn*256..+255] (64x256 f32 = 64KB) into LDS
  __syncthreads();
  {
    const float* hprow = hp + bn * 256;
    float* lhp = (float*)smem;
    #pragma unroll
    for (int qd = 0; qd < 8; ++qd) {
      int i = qd * 512 + tid;
      int b = i >> 6, col4 = i & 63;
      *(f4*)(lhp + b * 256 + col4 * 4) = *(const f4*)(hprow + (size_t)b * 1024 + col4 * 4);
    }
  }
  __syncthreads();
  const float* lhpf = (const float*)smem;

  int lg = kq;
  int bm = bm0 + bmL;
  float rs[8][4];
  #pragma unroll
  for (int mi = 0; mi < 8; ++mi)
    #pragma unroll
    for (int j = 0; j < 4; ++j) rs[mi][j] = 0.f;
  #pragma unroll
  for (int ni = 0; ni < 4; ++ni) {
    int colL = wc * 64 + ni * 16 + c;
    float vwa = vw[bn * 256 + colL];
    #pragma unroll
    for (int mi = 0; mi < 8; ++mi) {
      #pragma unroll
      for (int j = 0; j < 4; ++j) {
        int r = wr * 128 + mi * 16 + lg * 4 + j;
        int b = r & 63;
        float x = acc[mi][ni][j] + lhpf[b * 256 + colL];
        rs[mi][j] += fast_tanh(x) * vwa;
      }
    }
  }
  #pragma unroll
  for (int off = 1; off < 16; off <<= 1) {
    #pragma unroll
    for (int mi = 0; mi < 8; ++mi)
      #pragma unroll
      for (int j = 0; j < 4; ++j)
        rs[mi][j] += __shfl_xor(rs[mi][j], off, 64);
  }
  if (c == 0) {
    int p = bn * 4 + wc;
    #pragma unroll
    for (int mi = 0; mi < 8; ++mi)
      #pragma unroll
      for (int j = 0; j < 4; ++j) {
        int m = bm * 256 + wr * 128 + mi * 16 + lg * 4 + j;
        int b = m & 63, s = m >> 6;
        part[(size_t)p * MT + b * SS + s] = rs[mi][j];
      }
  }
}

// ---- sum 16 partials -> scores, softmax over s per b -> weights[b][s]
__global__ void k_softmax(const float* __restrict__ part, float* __restrict__ wt) {
  int b = blockIdx.x, tid = threadIdx.x, lane = tid & 63, wid = tid >> 6;
  __shared__ float red[8];
  float sc[8];
  float mx = -1e30f;
  #pragma unroll
  for (int i = 0; i < 8; ++i) {
    int s = tid + i * 256;
    float a = 0.f;
    #pragma unroll
    for (int p = 0; p < 16; ++p) a += part[(size_t)p * MT + b * SS + s];
    sc[i] = a; mx = fmaxf(mx, a);
  }
  for (int o = 1; o < 64; o <<= 1) mx = fmaxf(mx, __shfl_xor(mx, o, 64));
  if (lane == 0) red[wid] = mx;
  __syncthreads();
  mx = fmaxf(fmaxf(red[0], red[1]), fmaxf(red[2], red[3]));
  float sum = 0.f;
  #pragma unroll
  for (int i = 0; i < 8; ++i) { sc[i] = expf(sc[i] - mx); sum += sc[i]; }
  for (int o = 1; o < 64; o <<= 1) sum += __shfl_xor(sum, o, 64);
  if (lane == 0) red[4 + wid] = sum;
  __syncthreads();
  sum = red[4] + red[5] + red[6] + red[7];
  float inv = 1.f / sum;
  #pragma unroll
  for (int i = 0; i < 8; ++i) wt[b * SS + tid + i * 256] = sc[i] * inv;
}

// ---- context from f32 v: ctxp[cch][b][e] = sum_{s in chunk} w[b][s]*v[s][b][e]
__global__ void k_ctx_f32(const float* __restrict__ v, const float* __restrict__ wt,
                          float* __restrict__ ctxp) {
  int b = blockIdx.x, cch = blockIdx.y, tid = threadIdx.x;
  f4 acc = {0.f, 0.f, 0.f, 0.f};
  int s0 = cch * 128;
  const float* wrow = wt + b * SS;
  #pragma unroll 4
  for (int s = s0; s < s0 + 128; ++s) {
    float ws = wrow[s];
    const f4* vp = (const f4*)(v + (size_t)(s * 64 + b) * 1024);
    acc += vp[tid] * ws;
  }
  *(f4*)(ctxp + (size_t)(cch * 64 + b) * 1024 + tid * 4) = acc;
}

__global__ void k_out(const float* __restrict__ ctxp, float* __restrict__ out) {
  int b = blockIdx.x, tid = threadIdx.x;
  f4 acc = {0.f, 0.f, 0.f, 0.f};
  #pragma unroll
  for (int cch = 0; cch < 16; ++cch)
    acc += *(const f4*)(ctxp + (size_t)(cch * 64 + b) * 1024 + tid * 4);
  *(f4*)(out + b * 1024 + tid * 4) = acc;
}

extern "C" void kernel_launch(void* const* d_in, const int* in_sizes, int n_in,
                              void* d_out, int out_size, void* d_ws, size_t ws_size,
                              hipStream_t stream) {
  const float* hidden = (const float*)d_in[0];
  const float* v      = (const float*)d_in[1];   // (S, B, ENC) rows s*64+b
  const float* ww     = (const float*)d_in[2];   // (1024, 2048)
  const float* wbias  = (const float*)d_in[3];   // (1024)
  const float* vwgt   = (const float*)d_in[4];   // (1, 1024)
  float* out = (float*)d_out;

  char* ws = (char*)d_ws;
  float*          hp   = (float*)(ws);                                   // 256 KB
  unsigned char*  wq   = (unsigned char*)(ws + 262144);                  // 1 MB fp8 We
  float*          part = (float*)(ws + 262144 + 1048576);                // 8 MB
  float*          wt   = (float*)(ws + 262144 + 1048576 + 8388608);      // 512 KB
  float*          ctxp = (float*)(ws + 262144 + 1048576 + 8388608 + 524288); // 4 MB
  size_t fixed = 262144 + 1048576 + 8388608 + 524288 + 4194304;
  unsigned char*  vq   = (unsigned char*)(ws + fixed);                   // 128 MB fp8 v

  size_t avail = (ws_size > fixed) ? (ws_size - fixed) : 0;
  long rows_chunk = (long)(avail / 1024) & ~511L;      // fp8 row = 1024 B
  if (rows_chunk > MT) rows_chunk = MT;
  if (rows_chunk < 512) rows_chunk = 512;

  hipFuncSetAttribute((const void*)k_gemm, hipFuncAttributeMaxDynamicSharedMemorySize, 131072);

  k_packq<<<dim3(16, 4), 256, 0, stream>>>(ww, wq, 2048);
  k_hp<<<dim3(64, 4), 256, 0, stream>>>(hidden, ww, wbias, hp);

  for (long r0 = 0; r0 < MT; r0 += rows_chunk) {
    long nr = MT - r0; if (nr > rows_chunk) nr = rows_chunk;
    int nbm = (int)(nr / 256);
    k_packq<<<dim3((int)(nr / 64), 4), 256, 0, stream>>>(v + (size_t)r0 * 1024, vq, 1024);
    k_gemm<<<nbm * 4, 512, 131072, stream>>>(vq, wq, hp, vwgt, part, (int)(r0 / 256), nbm);
  }

  k_softmax<<<64, 256, 0, stream>>>(part, wt);
  k_ctx_f32<<<dim3(64, 16), 256, 0, stream>>>(v, wt, ctxp);
  k_out<<<64, 256, 0, stream>>>(ctxp, out);
}